// Round 1
// baseline (1688.205 us; speedup 1.0000x reference)
//
#include <hip/hip_runtime.h>
#include <math.h>

#define N_NODES 262144
#define NE      2000000
#define W_OUT   32

__device__ __forceinline__ float lrelu(float x) { return x >= 0.f ? x : 0.01f * x; }

// Deterministic float atomic-max via monotone integer mapping.
__device__ __forceinline__ void atomicMaxFloat(float* addr, float val) {
    if (!signbit(val)) {
        atomicMax((int*)addr, __float_as_int(val));
    } else {
        atomicMin((unsigned int*)addr, __float_as_uint(val));
    }
}

__global__ void fill_neginf(float4* p, int n4) {
    int stride = gridDim.x * blockDim.x;
    const float4 v = make_float4(-INFINITY, -INFINITY, -INFINITY, -INFINITY);
    for (int i = blockIdx.x * blockDim.x + threadIdx.x; i < n4; i += stride)
        p[i] = v;
}

// LinearBlock for the input projections: out[n][j] = lrelu(sum_k x[n][k]*w[k][j] + b[j])
// 32 threads per node, 8 nodes per 256-thread block.
template<int K>
__global__ void proj_kernel(const float* __restrict__ x, const float* __restrict__ w,
                            const float* __restrict__ b, float* __restrict__ out) {
    __shared__ float wl[K * 32];
    __shared__ float xl[8 * K];
    int t = threadIdx.x;
    for (int i = t; i < K * 32; i += 256) wl[i] = w[i];
    int nbase = blockIdx.x * 8;
    for (int i = t; i < 8 * K; i += 256) xl[i] = x[nbase * K + i];
    __syncthreads();
    int j = t & 31, ln = t >> 5;
    float acc = b[j];
#pragma unroll
    for (int k = 0; k < K; ++k) acc += xl[ln * K + k] * wl[k * 32 + j];
    out[nbase * 32 + t] = lrelu(acc);   // coalesced: base*32 + t
}

// Per-edge diff + scatter-max. 32 threads (channels) per edge, 8 edges/block.
__global__ void edge_max(const int* __restrict__ e0, const int* __restrict__ e1,
                         const float* __restrict__ src, const float* __restrict__ dst,
                         float* __restrict__ mx) {
    __shared__ int ls[8], ld[8];
    int t = threadIdx.x;
    int ebase = blockIdx.x * 8;
    if (t < 8) {
        if (ebase + t < NE) ls[t] = e0[ebase + t];
    } else if (t < 16) {
        if (ebase + t - 8 < NE) ld[t - 8] = e1[ebase + t - 8];
    }
    __syncthreads();
    int le = t >> 5, c = t & 31;
    int edge = ebase + le;
    if (edge < NE) {
        int s = ls[le], d = ld[le];
        float v = dst[d * 32 + c] - src[s * 32 + c];
        atomicMaxFloat(&mx[d * 32 + c], v);
    }
}

// Conv MLP: out[n] = dst[n] + lrelu(concat(dst[n], finite(mx[n])) @ w + b)
// 32 threads per node, 8 nodes per block. w is [64][32].
__global__ void conv_mlp(const float* __restrict__ dst, const float* __restrict__ mx,
                         const float* __restrict__ w, const float* __restrict__ b,
                         float* __restrict__ out) {
    __shared__ float wl[64 * 32];
    __shared__ float xl[8 * 64];
    int t = threadIdx.x;
    for (int i = t; i < 64 * 32; i += 256) wl[i] = w[i];
    int base = blockIdx.x * 256;          // element base = 8 nodes * 32 ch
    float dv = dst[base + t];
    float mv = mx[base + t];
    if (mv == -INFINITY) mv = 0.f;        // empty segments -> 0 (torch_scatter semantics)
    int ln = t >> 5, c = t & 31;
    xl[ln * 64 + c] = dv;
    xl[ln * 64 + 32 + c] = mv;
    __syncthreads();
    int j = c;
    float acc = b[j];
#pragma unroll
    for (int k = 0; k < 64; ++k) acc += xl[ln * 64 + k] * wl[k * 32 + j];
    out[base + t] = dv + lrelu(acc);
}

extern "C" void kernel_launch(void* const* d_in, const int* in_sizes, int n_in,
                              void* d_out, int out_size, void* d_ws, size_t ws_size,
                              hipStream_t stream) {
    const float* x_f  = (const float*)d_in[0];
    const float* x_e  = (const float*)d_in[1];
    const float* x_v  = (const float*)d_in[2];
    const int*   e_fe = (const int*)d_in[3];
    const int*   e_ev = (const int*)d_in[4];
    const int*   e_ef = (const int*)d_in[5];
    const int*   e_ve = (const int*)d_in[6];
    const float* wf    = (const float*)d_in[7];
    const float* bf    = (const float*)d_in[8];
    const float* we    = (const float*)d_in[9];
    const float* be    = (const float*)d_in[10];
    const float* wv    = (const float*)d_in[11];
    const float* bv    = (const float*)d_in[12];
    const float* w_f2e = (const float*)d_in[13];
    const float* b_f2e = (const float*)d_in[14];
    const float* w_e2v = (const float*)d_in[15];
    const float* b_e2v = (const float*)d_in[16];

    float* of = (float*)d_out;                  // x_f slot (holds xf0 then xf_out)
    float* oe = of + (size_t)N_NODES * W_OUT;   // x_e slot (holds xe0 then xe_out)
    float* ov = oe + (size_t)N_NODES * W_OUT;   // x_v slot (holds xv0 then xv_out)

    float* xe1 = (float*)d_ws;                  // x_e after F2E conv
    float* mx  = xe1 + (size_t)N_NODES * W_OUT; // segment-max scratch

    const int NW = N_NODES * W_OUT;
    dim3 blk(256);

    // Input projections
    proj_kernel<4><<<N_NODES / 8, blk, 0, stream>>>(x_f, wf, bf, of);
    proj_kernel<6><<<N_NODES / 8, blk, 0, stream>>>(x_e, we, be, oe);
    proj_kernel<3><<<N_NODES / 8, blk, 0, stream>>>(x_v, wv, bv, ov);

    auto conv = [&](const float* src, const float* dstb, const int* e,
                    const float* w, const float* bias, float* out) {
        fill_neginf<<<2048, blk, 0, stream>>>((float4*)mx, NW / 4);
        edge_max<<<NE / 8, blk, 0, stream>>>(e, e + NE, src, dstb, mx);
        conv_mlp<<<N_NODES / 8, blk, 0, stream>>>(dstb, mx, w, bias, out);
    };

    conv(of,  oe,  e_fe, w_f2e, b_f2e, xe1);  // x_e1 = F2E(x_f0, x_e0)
    conv(xe1, ov,  e_ev, w_e2v, b_e2v, ov);   // x_v1 = E2V(x_e1, x_v0)   (in-place)
    conv(xe1, of,  e_ef, w_f2e, b_f2e, of);   // x_f1 = F2E(x_e1, x_f0)   (in-place)
    conv(ov,  xe1, e_ve, w_f2e, b_f2e, oe);   // x_e2 = F2E(x_v1, x_e1)
}

// Round 2
// 1588.478 us; speedup vs baseline: 1.0628x; 1.0628x over previous
//
#include <hip/hip_runtime.h>
#include <math.h>

#define N_NODES 262144
#define NE      2000000
#define W_OUT   32
#define NBLK    1024          // N_NODES / 256

__device__ __forceinline__ float lrelu(float x) { return x >= 0.f ? x : 0.01f * x; }

// ---------------- input projections ----------------
// out[n][j] = lrelu(sum_k x[n][k]*w[k][j] + b[j]); 32 threads/node, 8 nodes/block
template<int K>
__global__ void proj_kernel(const float* __restrict__ x, const float* __restrict__ w,
                            const float* __restrict__ b, float* __restrict__ out) {
    __shared__ float wl[K * 32];
    __shared__ float xl[8 * K];
    int t = threadIdx.x;
    for (int i = t; i < K * 32; i += 256) wl[i] = w[i];
    int nbase = blockIdx.x * 8;
    for (int i = t; i < 8 * K; i += 256) xl[i] = x[nbase * K + i];
    __syncthreads();
    int j = t & 31, ln = t >> 5;
    float acc = b[j];
#pragma unroll
    for (int k = 0; k < K; ++k) acc += xl[ln * K + k] * wl[k * 32 + j];
    out[nbase * 32 + t] = lrelu(acc);
}

// ---------------- CSR build ----------------
__global__ void zero_ints(int* __restrict__ p, int n) {
    int i = blockIdx.x * blockDim.x + threadIdx.x;
    if (i < n) p[i] = 0;
}

__global__ void hist_kernel(const int* __restrict__ e1, int* __restrict__ count) {
    int i = blockIdx.x * blockDim.x + threadIdx.x;
    if (i < NE) atomicAdd(&count[e1[i]], 1);
}

// block-level exclusive scan (256 elems/block), emit block sums
__global__ void scan1(const int* __restrict__ count, int* __restrict__ offs,
                      int* __restrict__ bsum) {
    __shared__ int sh[256];
    int t = threadIdx.x, g = blockIdx.x * 256 + t;
    int v = count[g];
    sh[t] = v; __syncthreads();
    for (int d = 1; d < 256; d <<= 1) {
        int x = (t >= d) ? sh[t - d] : 0;
        __syncthreads();
        sh[t] += x;
        __syncthreads();
    }
    offs[g] = sh[t] - v;            // exclusive within block
    if (t == 255) bsum[blockIdx.x] = sh[255];
}

// single-block exclusive scan of the 1024 block sums
__global__ void scan2(int* __restrict__ bsum) {
    __shared__ int sh[NBLK];
    int t = threadIdx.x;
    int v = bsum[t];
    sh[t] = v; __syncthreads();
    for (int d = 1; d < NBLK; d <<= 1) {
        int x = (t >= d) ? sh[t - d] : 0;
        __syncthreads();
        sh[t] += x;
        __syncthreads();
    }
    bsum[t] = sh[t] - v;            // exclusive
}

__global__ void scan3(int* __restrict__ offs, int* __restrict__ cursor,
                      const int* __restrict__ bsum) {
    int g = blockIdx.x * 256 + threadIdx.x;
    int v = offs[g] + bsum[blockIdx.x];
    offs[g] = v;
    cursor[g] = v;
    if (g == 0) offs[N_NODES] = NE;
}

__global__ void scatter_kernel(const int* __restrict__ e0, const int* __restrict__ e1,
                               int* __restrict__ cursor, int* __restrict__ srcidx) {
    int i = blockIdx.x * blockDim.x + threadIdx.x;
    if (i < NE) {
        int d = e1[i];
        int pos = atomicAdd(&cursor[d], 1);
        srcidx[pos] = e0[i];
    }
}

// ---------------- fused segmented-min + MLP + residual ----------------
// maxes[d] = dst[d] - min_{s in nbrs(d)} src[s]   (bit-exact vs max(dst-src): fp32 sub is monotone)
// out[d]   = dst[d] + lrelu(concat(dst[d], deg? maxes : 0) @ w + b)
__global__ void reduce_mlp(const int* __restrict__ offs, const int* __restrict__ srcidx,
                           const float* __restrict__ src, const float* __restrict__ dst,
                           const float* __restrict__ w, const float* __restrict__ b,
                           float* __restrict__ out) {
    __shared__ float wl[64 * 32];
    __shared__ float xl[8 * 64];
    int t = threadIdx.x;
    for (int i = t; i < 64 * 32; i += 256) wl[i] = w[i];
    int ln = t >> 5, c = t & 31;
    int node = blockIdx.x * 8 + ln;
    int beg = offs[node], end = offs[node + 1];
    float mn = INFINITY;
    for (int i = beg; i < end; ++i) {
        int s = srcidx[i];                       // wave-uniform per node
        mn = fminf(mn, src[s * 32 + c]);         // coalesced 128B gather
    }
    float dv = dst[node * 32 + c];
    float mx = (beg < end) ? (dv - mn) : 0.0f;
    xl[ln * 64 + c] = dv;
    xl[ln * 64 + 32 + c] = mx;
    __syncthreads();
    float acc = b[c];
#pragma unroll
    for (int k = 0; k < 64; ++k) acc += xl[ln * 64 + k] * wl[k * 32 + c];
    out[node * 32 + c] = dv + lrelu(acc);
}

extern "C" void kernel_launch(void* const* d_in, const int* in_sizes, int n_in,
                              void* d_out, int out_size, void* d_ws, size_t ws_size,
                              hipStream_t stream) {
    const float* x_f  = (const float*)d_in[0];
    const float* x_e  = (const float*)d_in[1];
    const float* x_v  = (const float*)d_in[2];
    const int*   e_fe = (const int*)d_in[3];
    const int*   e_ev = (const int*)d_in[4];
    const int*   e_ef = (const int*)d_in[5];
    const int*   e_ve = (const int*)d_in[6];
    const float* wf    = (const float*)d_in[7];
    const float* bf    = (const float*)d_in[8];
    const float* we    = (const float*)d_in[9];
    const float* be    = (const float*)d_in[10];
    const float* wv    = (const float*)d_in[11];
    const float* bv    = (const float*)d_in[12];
    const float* w_f2e = (const float*)d_in[13];
    const float* b_f2e = (const float*)d_in[14];
    const float* w_e2v = (const float*)d_in[15];
    const float* b_e2v = (const float*)d_in[16];

    float* of = (float*)d_out;                  // x_f slot
    float* oe = of + (size_t)N_NODES * W_OUT;   // x_e slot
    float* ov = oe + (size_t)N_NODES * W_OUT;   // x_v slot

    const int NW = N_NODES * W_OUT;

    // workspace: xe1(32MB) | srcidx(8MB) | offs(N+1) | cursor(N) | count(N) | bsum(1024)
    float* xe1    = (float*)d_ws;
    int*   srcidx = (int*)(xe1 + NW);
    int*   offs   = srcidx + NE;
    int*   cursor = offs + (N_NODES + 1);
    int*   count  = cursor + N_NODES;
    int*   bsum   = count + N_NODES;

    dim3 blk(256);
    const int egrid = (NE + 255) / 256;

    // input projections
    proj_kernel<4><<<N_NODES / 8, blk, 0, stream>>>(x_f, wf, bf, of);
    proj_kernel<6><<<N_NODES / 8, blk, 0, stream>>>(x_e, we, be, oe);
    proj_kernel<3><<<N_NODES / 8, blk, 0, stream>>>(x_v, wv, bv, ov);

    auto conv = [&](const float* src, const float* dstb, const int* e,
                    const float* w, const float* bias, float* out) {
        const int* e0 = e;
        const int* e1 = e + NE;
        zero_ints<<<NBLK, blk, 0, stream>>>(count, N_NODES);
        hist_kernel<<<egrid, blk, 0, stream>>>(e1, count);
        scan1<<<NBLK, blk, 0, stream>>>(count, offs, bsum);
        scan2<<<1, NBLK, 0, stream>>>(bsum);
        scan3<<<NBLK, blk, 0, stream>>>(offs, cursor, bsum);
        scatter_kernel<<<egrid, blk, 0, stream>>>(e0, e1, cursor, srcidx);
        reduce_mlp<<<N_NODES / 8, blk, 0, stream>>>(offs, srcidx, src, dstb, w, bias, out);
    };

    conv(of,  oe,  e_fe, w_f2e, b_f2e, xe1);  // x_e1 = F2E(x_f0, x_e0)
    conv(xe1, ov,  e_ev, w_e2v, b_e2v, ov);   // x_v1 = E2V(x_e1, x_v0)   in-place
    conv(xe1, of,  e_ef, w_f2e, b_f2e, of);   // x_f1 = F2E(x_e1, x_f0)   in-place
    conv(ov,  xe1, e_ve, w_f2e, b_f2e, oe);   // x_e2 = F2E(x_v1, x_e1)
}

// Round 3
// 646.937 us; speedup vs baseline: 2.6095x; 2.4554x over previous
//
#include <hip/hip_runtime.h>
#include <math.h>

#define N_NODES 262144
#define NE      2000000
#define W_OUT   32

#define NBINS          256
#define BIN_SHIFT      10
#define NODES_PER_BIN  1024        // N_NODES / NBINS
#define CAP            9216        // max edges per bin (mean 7813, sigma ~88)
#define EPT            32          // edges per thread in bin_pass

__device__ __forceinline__ float lrelu(float x) { return x >= 0.f ? x : 0.01f * x; }

// ---------------- input projections ----------------
// out[n][j] = lrelu(sum_k x[n][k]*w[k][j] + b[j]); 32 threads/node, 8 nodes/block
template<int K>
__global__ void proj_kernel(const float* __restrict__ x, const float* __restrict__ w,
                            const float* __restrict__ b, float* __restrict__ out) {
    __shared__ float wl[K * 32];
    __shared__ float xl[8 * K];
    int t = threadIdx.x;
    for (int i = t; i < K * 32; i += 256) wl[i] = w[i];
    int nbase = blockIdx.x * 8;
    for (int i = t; i < 8 * K; i += 256) xl[i] = x[nbase * K + i];
    __syncthreads();
    int j = t & 31, ln = t >> 5;
    float acc = b[j];
#pragma unroll
    for (int k = 0; k < K; ++k) acc += xl[ln * K + k] * wl[k * 32 + j];
    out[nbase * 32 + t] = lrelu(acc);
}

// ---------------- pass A: bin edges by dst>>10 ----------------
// entry = (d_low10 << 18) | src18.  Writes confined to 256 hot line-regions -> L2-absorbed.
__global__ void bin_pass(const int* __restrict__ e0, const int* __restrict__ e1,
                         int* __restrict__ gcur, unsigned int* __restrict__ buckets) {
    __shared__ unsigned int hist[NBINS];
    __shared__ unsigned int lcur[NBINS];
    __shared__ unsigned int gbase[NBINS];
    int t = threadIdx.x;
    hist[t] = 0;                      // blockDim.x == 256 == NBINS
    __syncthreads();
    int base = blockIdx.x * (256 * EPT);
    for (int k = 0; k < EPT; ++k) {
        int i = base + k * 256 + t;   // coalesced
        if (i < NE) atomicAdd(&hist[e1[i] >> BIN_SHIFT], 1u);
    }
    __syncthreads();
    gbase[t] = atomicAdd((unsigned int*)&gcur[t], hist[t]);
    lcur[t] = 0;
    __syncthreads();
    for (int k = 0; k < EPT; ++k) {
        int i = base + k * 256 + t;
        if (i < NE) {
            int d = e1[i];
            int s = e0[i];
            int bin = d >> BIN_SHIFT;
            unsigned int pos = gbase[bin] + atomicAdd(&lcur[bin], 1u);
            if (pos < CAP)
                buckets[(size_t)bin * CAP + pos] =
                    ((unsigned int)(d & (NODES_PER_BIN - 1)) << 18) | (unsigned int)s;
        }
    }
}

// ---------------- pass B: per-bin counting sort + segmented min + MLP + residual ----------------
// maxes[d] = dst[d] - min_{s in nbrs(d)} src[s]  (bit-exact vs max(dst-src): fp32 sub monotone)
// out[d]   = dst[d] + lrelu(concat(dst[d], deg? maxes : 0) @ w + b)
__global__ __launch_bounds__(1024)
void binreduce_mlp(const int* __restrict__ gcur, const unsigned int* __restrict__ buckets,
                   const float* __restrict__ src, const float* __restrict__ dst,
                   const float* __restrict__ w, const float* __restrict__ b,
                   float* __restrict__ out) {
    __shared__ float wl[64 * 32];                       // 8 KB
    __shared__ unsigned int offs_l[NODES_PER_BIN + 1];  // 4 KB
    __shared__ unsigned int cnt[NODES_PER_BIN];         // 4 KB
    __shared__ unsigned int sorted_s[CAP];              // 36 KB
    __shared__ float xrow[32][64];                      // 8 KB
    int t = threadIdx.x;
    int bin = blockIdx.x;
    int nb = min(gcur[bin], CAP);
    const unsigned int* bk = buckets + (size_t)bin * CAP;

    for (int i = t; i < 64 * 32; i += 1024) wl[i] = w[i];
    cnt[t & (NODES_PER_BIN - 1)] = 0;   // blockDim == 1024 == NODES_PER_BIN
    __syncthreads();

    // histogram over low-10 dst bits
    for (int i = t; i < nb; i += 1024)
        atomicAdd(&cnt[bk[i] >> 18], 1u);
    __syncthreads();

    // Hillis-Steele inclusive scan -> exclusive offsets
    unsigned int v = cnt[t];
    offs_l[t] = v;
    __syncthreads();
    for (int d = 1; d < NODES_PER_BIN; d <<= 1) {
        unsigned int x = (t >= d) ? offs_l[t - d] : 0u;
        __syncthreads();
        offs_l[t] += x;
        __syncthreads();
    }
    unsigned int inc = offs_l[t];
    __syncthreads();
    offs_l[t] = inc - v;
    if (t == NODES_PER_BIN - 1) offs_l[NODES_PER_BIN] = inc;
    cnt[t] = 0;                         // reuse as scatter cursors
    __syncthreads();

    // scatter src indices into per-node segments (LDS)
    for (int i = t; i < nb; i += 1024) {
        unsigned int p = bk[i];
        unsigned int dl = p >> 18;
        unsigned int pos = offs_l[dl] + atomicAdd(&cnt[dl], 1u);
        sorted_s[pos] = p & 0x3FFFFu;
    }
    __syncthreads();

    // per-node: 32 half-waves, each processes nodes hw, hw+32, ...
    int hw = t >> 5;
    int c = t & 31;
    float bc = b[c];
    for (int ln = hw; ln < NODES_PER_BIN; ln += 32) {
        int g = bin * NODES_PER_BIN + ln;
        unsigned int beg = offs_l[ln], end = offs_l[ln + 1];
        float mn = INFINITY;
        for (unsigned int i = beg; i < end; ++i) {
            unsigned int s = sorted_s[i];                 // broadcast LDS read
            mn = fminf(mn, src[(size_t)s * 32 + c]);      // coalesced 128B gather
        }
        float dv = dst[(size_t)g * 32 + c];
        float mx = (beg < end) ? (dv - mn) : 0.0f;
        xrow[hw][c] = dv;
        xrow[hw][32 + c] = mx;
        __threadfence_block();          // order LDS write -> broadcast read within wave
        float acc = bc;
#pragma unroll 8
        for (int k = 0; k < 64; ++k)
            acc += xrow[hw][k] * wl[k * 32 + c];
        out[(size_t)g * 32 + c] = dv + lrelu(acc);
    }
}

extern "C" void kernel_launch(void* const* d_in, const int* in_sizes, int n_in,
                              void* d_out, int out_size, void* d_ws, size_t ws_size,
                              hipStream_t stream) {
    const float* x_f  = (const float*)d_in[0];
    const float* x_e  = (const float*)d_in[1];
    const float* x_v  = (const float*)d_in[2];
    const int*   e_fe = (const int*)d_in[3];
    const int*   e_ev = (const int*)d_in[4];
    const int*   e_ef = (const int*)d_in[5];
    const int*   e_ve = (const int*)d_in[6];
    const float* wf    = (const float*)d_in[7];
    const float* bf    = (const float*)d_in[8];
    const float* we    = (const float*)d_in[9];
    const float* be    = (const float*)d_in[10];
    const float* wv    = (const float*)d_in[11];
    const float* bv    = (const float*)d_in[12];
    const float* w_f2e = (const float*)d_in[13];
    const float* b_f2e = (const float*)d_in[14];
    const float* w_e2v = (const float*)d_in[15];
    const float* b_e2v = (const float*)d_in[16];

    float* of = (float*)d_out;                  // x_f slot
    float* oe = of + (size_t)N_NODES * W_OUT;   // x_e slot
    float* ov = oe + (size_t)N_NODES * W_OUT;   // x_v slot

    const int NW = N_NODES * W_OUT;

    // workspace: xe1 (32MB) | buckets (9.4MB) | gcur (1KB)
    float*        xe1     = (float*)d_ws;
    unsigned int* buckets = (unsigned int*)(xe1 + NW);
    int*          gcur    = (int*)(buckets + (size_t)NBINS * CAP);

    dim3 blk(256);
    const int bgrid = (NE + 256 * EPT - 1) / (256 * EPT);   // 245

    proj_kernel<4><<<N_NODES / 8, blk, 0, stream>>>(x_f, wf, bf, of);
    proj_kernel<6><<<N_NODES / 8, blk, 0, stream>>>(x_e, we, be, oe);
    proj_kernel<3><<<N_NODES / 8, blk, 0, stream>>>(x_v, wv, bv, ov);

    auto conv = [&](const float* src, const float* dstb, const int* e,
                    const float* w, const float* bias, float* out) {
        hipMemsetAsync(gcur, 0, NBINS * sizeof(int), stream);
        bin_pass<<<bgrid, blk, 0, stream>>>(e, e + NE, gcur, buckets);
        binreduce_mlp<<<NBINS, dim3(1024), 0, stream>>>(gcur, buckets, src, dstb, w, bias, out);
    };

    conv(of,  oe,  e_fe, w_f2e, b_f2e, xe1);  // x_e1 = F2E(x_f0, x_e0)
    conv(xe1, ov,  e_ev, w_e2v, b_e2v, ov);   // x_v1 = E2V(x_e1, x_v0)   in-place
    conv(xe1, of,  e_ef, w_f2e, b_f2e, of);   // x_f1 = F2E(x_e1, x_f0)   in-place
    conv(ov,  xe1, e_ve, w_f2e, b_f2e, oe);   // x_e2 = F2E(x_v1, x_e1)
}